// Round 7
// baseline (155.748 us; speedup 1.0000x reference)
//
#include <hip/hip_runtime.h>

#define B_ 16
#define N_ 128
#define A_ 32
#define O_ 64
#define VD_ 768
#define H_ 1024

typedef short s16x8 __attribute__((ext_vector_type(8)));
typedef short s16x4 __attribute__((ext_vector_type(4)));
typedef float f32x4 __attribute__((ext_vector_type(4)));

#define MFMA(a, b, c) __builtin_amdgcn_mfma_f32_16x16x32_bf16(a, b, c, 0, 0, 0)

__device__ __forceinline__ short bf_hi(float x) {
    return (short)(__float_as_uint(x) >> 16);
}
__device__ __forceinline__ short bf_lo(float x) {
    float r = x - __uint_as_float(__float_as_uint(x) & 0xffff0000u);
    return (short)(__float_as_uint(r) >> 16);
}
__device__ __forceinline__ void cvt8(const float4& f0, const float4& f1,
                                     s16x8& hi, s16x8& lo) {
    const float ff[8] = {f0.x, f0.y, f0.z, f0.w, f1.x, f1.y, f1.z, f1.w};
    #pragma unroll
    for (int e = 0; e < 8; ++e) { hi[e] = bf_hi(ff[e]); lo[e] = bf_lo(ff[e]); }
}

__device__ __forceinline__ void gload16(const void* g, void* l) {
    __builtin_amdgcn_global_load_lds(
        (const __attribute__((address_space(1))) void*)g,
        (__attribute__((address_space(3))) void*)l, 16, 0, 0);
}

// ---------------------------------------------------------------------------
// Pre-split f32 -> (hi bf16, lo bf16) for obj, q, vw, qw.  (unchanged)
// ---------------------------------------------------------------------------
__global__ __launch_bounds__(256)
void cvt_split(const float* __restrict__ obj, const float* __restrict__ q,
               const float* __restrict__ vw, const float* __restrict__ qw,
               short* __restrict__ objh, short* __restrict__ objl,
               short* __restrict__ qh, short* __restrict__ ql,
               short* __restrict__ vwh, short* __restrict__ vwl,
               short* __restrict__ qwh, short* __restrict__ qwl)
{
    const int bid = blockIdx.x;
    const float* src; short* hi; short* lo; int base4;
    if (bid < 192)      { src = obj; hi = objh; lo = objl; base4 = bid * 1024; }
    else if (bid < 576) { src = q;   hi = qh;   lo = ql;   base4 = (bid - 192) * 1024; }
    else if (bid < 768) { src = vw;  hi = vwh;  lo = vwl;  base4 = (bid - 576) * 1024; }
    else                { src = qw;  hi = qwh;  lo = qwl;  base4 = (bid - 768) * 1024; }
    #pragma unroll
    for (int it = 0; it < 4; ++it) {
        const size_t f4 = (size_t)base4 + it * 256 + threadIdx.x;
        const float4 v = *(const float4*)(src + f4 * 4);
        const float ff[4] = {v.x, v.y, v.z, v.w};
        s16x4 h4, l4;
        #pragma unroll
        for (int e = 0; e < 4; ++e) { h4[e] = bf_hi(ff[e]); l4[e] = bf_lo(ff[e]); }
        *(s16x4*)(hi + f4 * 4) = h4;
        *(s16x4*)(lo + f4 * 4) = l4;
    }
}

// ---------------------------------------------------------------------------
// Unified split-bf16 NT GEMM on pre-split operands (unchanged; verified).
// ---------------------------------------------------------------------------
__global__ __launch_bounds__(256)
void gemm_split(const short* __restrict__ objh, const short* __restrict__ objl,
                const short* __restrict__ qh, const short* __restrict__ ql,
                const short* __restrict__ vwh, const short* __restrict__ vwl,
                const short* __restrict__ qwh, const short* __restrict__ qwl,
                const float* __restrict__ qb, const float* __restrict__ lwp,
                short* __restrict__ Wth, float* __restrict__ ub)
{
    __shared__ __align__(16) short lds[4 * 4096];   // Xh | Xl | Bh | Bl (64x64 each)
    const int bid = blockIdx.x;
    const bool isA = bid < 256;
    const int lb_ = isA ? bid : bid - 256;
    const int r0 = (lb_ >> 4) * 64;
    const int h0 = (lb_ & 15) * 64;
    const short* Xh = isA ? objh : qh;
    const short* Xl = isA ? objl : ql;
    const short* Bh = isA ? vwh : qwh;
    const short* Bl = isA ? vwl : qwl;

    const int tid = threadIdx.x;
    const int w = tid >> 6, l = tid & 63;
    const int wm = (w >> 1) * 32, wn = (w & 1) * 32;
    const int g = l >> 4, c16 = l & 15;

    const int row0 = tid >> 3, u0 = (tid & 7) ^ (row0 & 7);
    const int unit1 = 256 + tid;
    const int row1 = unit1 >> 3, u1 = (unit1 & 7) ^ (row1 & 7);
    const short* pXh = Xh + (size_t)r0 * VD_;
    const short* pXl = Xl + (size_t)r0 * VD_;
    const short* pBh = Bh + (size_t)h0 * VD_;
    const short* pBl = Bl + (size_t)h0 * VD_;
    int go0 = row0 * VD_ + u0 * 8;
    int go1 = row1 * VD_ + u1 * 8;
    short* const d0 = &lds[w * 512];

    f32x4 acc[2][2] = {};

    for (int c = 0; c < VD_ / 64; ++c) {
        __syncthreads();
        gload16(pXh + go0, d0);
        gload16(pXh + go1, d0 + 2048);
        gload16(pXl + go0, d0 + 4096);
        gload16(pXl + go1, d0 + 4096 + 2048);
        gload16(pBh + go0, d0 + 8192);
        gload16(pBh + go1, d0 + 8192 + 2048);
        gload16(pBl + go0, d0 + 12288);
        gload16(pBl + go1, d0 + 12288 + 2048);
        go0 += 64; go1 += 64;
        __syncthreads();
        #pragma unroll
        for (int s = 0; s < 2; ++s) {
            s16x8 ah[2], al[2], bh2[2], bl2[2];
            #pragma unroll
            for (int i = 0; i < 2; ++i) {
                const int m = wm + i * 16 + c16;
                const int us = (((s * 4 + g) ^ (m & 7)) * 8);
                ah[i]  = *(const s16x8*)&lds[m * 64 + us];
                al[i]  = *(const s16x8*)&lds[4096 + m * 64 + us];
                const int n = wn + i * 16 + c16;
                const int vs = (((s * 4 + g) ^ (n & 7)) * 8);
                bh2[i] = *(const s16x8*)&lds[8192 + n * 64 + vs];
                bl2[i] = *(const s16x8*)&lds[12288 + n * 64 + vs];
            }
            #pragma unroll
            for (int i = 0; i < 2; ++i)
                #pragma unroll
                for (int j = 0; j < 2; ++j) {
                    acc[i][j] = MFMA(ah[i], bh2[j], acc[i][j]);
                    acc[i][j] = MFMA(ah[i], bl2[j], acc[i][j]);
                    acc[i][j] = MFMA(al[i], bh2[j], acc[i][j]);
                }
        }
    }

    #pragma unroll
    for (int i = 0; i < 2; ++i)
        #pragma unroll
        for (int j = 0; j < 2; ++j) {
            const int h = h0 + wn + j * 16 + c16;
            if (isA) {
                const int o = wm + i * 16 + g * 4;
                s16x4 hi4;
                #pragma unroll
                for (int r = 0; r < 4; ++r) hi4[r] = bf_hi(acc[i][j][r]);
                const size_t dst = ((size_t)(lb_ >> 4) * H_ + h) * O_ + o;
                *(s16x4*)&Wth[dst] = hi4;
            } else {
                const float bv = qb[h], sv = lwp[h];
                #pragma unroll
                for (int r = 0; r < 4; ++r) {
                    const int m = r0 + wm + i * 16 + g * 4 + r;
                    ub[(size_t)m * H_ + h] = fmaxf(acc[i][j][r] + bv, 0.f) * sv;
                }
            }
        }
}

// ---------------------------------------------------------------------------
// Fused v3: per (b, n-pair) block, full 1024-h sweep + softmax + att2 @ att1.
// W staged hi-only through THREE LDS buffers, 2 chunks ahead, raw s_barrier +
// counted s_waitcnt vmcnt(2) (never drains the deepest prefetch). The chunk
// loop contains no global loads except the 2 STAGEW gloads (u0/u1 come from
// an LDS table, vb from 16 unrolled registers) so vmcnt counting is exact.
// LDS 49 KB -> 3 blocks/CU. Compute math identical to the verified v2.
// ---------------------------------------------------------------------------
__global__ __launch_bounds__(256, 3)
void fused_logits(const float* __restrict__ att1, const short* __restrict__ Wth,
                  const float* __restrict__ ub, const float* __restrict__ vb,
                  const int* __restrict__ tags, const int* __restrict__ tptr,
                  const float* __restrict__ lbptr, float* __restrict__ out)
{
    __shared__ __align__(16) short Ah[64 * 64], Al[64 * 64];   // 16 KB
    __shared__ __align__(16) short Wc[3][64 * 64];             // 24 KB hi-only
    __shared__ float uvb2[2][1024];                            // 8 KB (u0,u1)
    __shared__ float lgp[4][64];                               // 1 KB

    const int blk = blockIdx.x;          // b*64 + pair
    const int b = blk >> 6;
    const int n0 = (blk & 63) * 2;
    const int tid = threadIdx.x;
    const size_t base_row = (size_t)(b * N_ + n0) * A_;

    {   // stage att1 tile as swizzled split-bf16 (once per pair)
        const int row = tid >> 2, qq = tid & 3;
        const float* src = att1 + (base_row + row) * O_ + qq * 16;
        #pragma unroll
        for (int uu = 0; uu < 2; ++uu) {
            const float4 f0 = *(const float4*)(src + uu * 8);
            const float4 f1 = *(const float4*)(src + uu * 8 + 4);
            const int us = ((qq * 2 + uu) ^ (row & 7)) * 8;
            s16x8 hi, lo; cvt8(f0, f1, hi, lo);
            *(s16x8*)&Ah[row * 64 + us] = hi;
            *(s16x8*)&Al[row * 64 + us] = lo;
        }
    }

    const int w = tid >> 6, l = tid & 63;
    const int g = l >> 4, c16 = l & 15;

    // u0/u1 rows -> LDS table (float4 coalesced)
    {
        const float* u0g = ub + (size_t)(b * N_ + n0) * H_;
        const float* u1g = u0g + H_;
        *(float4*)&uvb2[0][tid * 4] = *(const float4*)(u0g + tid * 4);
        *(float4*)&uvb2[1][tid * 4] = *(const float4*)(u1g + tid * 4);
    }

    // vb -> 16 registers (statically indexed after unroll)
    float vbr[16];
    #pragma unroll
    for (int c = 0; c < 16; ++c) vbr[c] = vb[c * 64 + w * 16 + c16];

    // W chunk staging: linear LDS dest (unit = tid + k*256), pre-swizzled src
    const int row0 = tid >> 3;                        // 0..31
    const int usrc = (tid & 7) ^ (row0 & 7);
    const int off0 = row0 * 64 + usrc * 8;            // shorts
    const int off1 = off0 + 2048;
    const short* pWh = Wth + (size_t)b * H_ * O_;

#define STAGEW(BUF, CI) do { \
        const short* ph_ = pWh + (size_t)(CI) * 4096; \
        gload16(ph_ + off0, &Wc[BUF][w * 512]); \
        gload16(ph_ + off1, &Wc[BUF][w * 512 + 2048]); \
    } while (0)

    STAGEW(0, 0);
    STAGEW(1, 1);
    __syncthreads();     // full drain (vmcnt 0 + lgkm 0): clean vmcnt baseline

    // A fragments, held for the whole sweep (16 frags = 64 VGPRs)
    s16x8 ahf[4][2], alf[4][2];
    #pragma unroll
    for (int i = 0; i < 4; ++i)
        #pragma unroll
        for (int s = 0; s < 2; ++s) {
            const int m = i * 16 + c16;
            const int us = ((s * 4 + g) ^ (m & 7)) * 8;
            ahf[i][s] = *(const s16x8*)&Ah[m * 64 + us];
            alf[i][s] = *(const s16x8*)&Al[m * 64 + us];
        }

    const int sr = c16 & 7;
    const int rbase = (w * 16 + c16) * 64;
    const int ubo0 = (g ^ sr) * 8;
    const int ubo1 = ((g + 4) ^ sr) * 8;
    const int ulane = w * 16 + c16;

    f32x4 part[4] = {};

    #pragma unroll
    for (int t = 0; t < 16; ++t) {
        if (t < 14) STAGEW((t + 2) % 3, t + 2);    // only vmem ops in loop
        const float vbv = vbr[t];
        const float uu0 = uvb2[0][t * 64 + ulane];
        const float uu1 = uvb2[1][t * 64 + ulane];
        const s16x8 bh0 = *(const s16x8*)&Wc[t % 3][rbase + ubo0];
        const s16x8 bh1 = *(const s16x8*)&Wc[t % 3][rbase + ubo1];
        #pragma unroll
        for (int i = 0; i < 4; ++i) {
            f32x4 acc = {};
            acc = MFMA(ahf[i][0], bh0, acc);
            acc = MFMA(alf[i][0], bh0, acc);
            acc = MFMA(ahf[i][1], bh1, acc);
            acc = MFMA(alf[i][1], bh1, acc);
            const float uu = (i < 2) ? uu0 : uu1;
            #pragma unroll
            for (int r = 0; r < 4; ++r)
                part[i][r] += fmaxf(acc[r] + vbv, 0.f) * uu;
        }
        // in flight: stage(t+1) [2 loads] + stage(t+2) [2 loads if issued].
        // vmcnt(2) => stage(t+1) retired; deepest prefetch stays in flight.
        if (t < 14)       asm volatile("s_waitcnt vmcnt(2)" ::: "memory");
        else if (t == 14) asm volatile("s_waitcnt vmcnt(0)" ::: "memory");
        if (t < 15) {
            __builtin_amdgcn_s_barrier();
            __builtin_amdgcn_sched_barrier(0);   // pin STAGE/ds_read across
        }
    }
#undef STAGEW

    #pragma unroll
    for (int i = 0; i < 4; ++i)
        #pragma unroll
        for (int r = 0; r < 4; ++r) {
            float v = part[i][r];
            v += __shfl_xor(v, 1, 64);
            v += __shfl_xor(v, 2, 64);
            v += __shfl_xor(v, 4, 64);
            v += __shfl_xor(v, 8, 64);
            if (c16 == 0) lgp[w][i * 16 + g * 4 + r] = v;
        }
    __syncthreads();

    float* sml = &uvb2[0][0];     // uvb2 dead after chunk loop; reuse 256 B
    if (tid < 64) {
        const float tf = (float)(*tptr);
        const float lsum = lgp[0][tid] + lgp[1][tid] + lgp[2][tid] + lgp[3][tid];
        const float lv = (lsum + *lbptr) / tf;
        const int tg = tags[base_row + tid];
        sml[tid] = (tg > 0) ? lv : -1e30f;
    }
    __syncthreads();

    if (tid < 128) {
        const int nn = tid >> 6, o = tid & 63;
        const float* lr = &sml[nn * 32];
        const int uo = (o >> 3);          // 8-elem unit of column o
        const int oe = (o & 7);
        float m = -3.0e38f;
        #pragma unroll
        for (int a = 0; a < 32; ++a) m = fmaxf(m, lr[a]);
        float s = 0.f, accum = 0.f;
        #pragma unroll
        for (int a = 0; a < 32; ++a) {
            const int row = nn * 32 + a;
            const int idx = row * 64 + ((uo ^ (row & 7)) * 8 + oe);
            const float a1 =
                __uint_as_float(((unsigned)(unsigned short)Ah[idx]) << 16) +
                __uint_as_float(((unsigned)(unsigned short)Al[idx]) << 16);
            const float e = __expf(lr[a] - m);
            s += e;
            accum += e * a1;
        }
        out[(size_t)(b * N_ + n0 + nn) * O_ + o] = accum / s;
    }
}

extern "C" void kernel_launch(void* const* d_in, const int* in_sizes, int n_in,
                              void* d_out, int out_size, void* d_ws, size_t ws_size,
                              hipStream_t stream)
{
    const float* q    = (const float*)d_in[0];
    const float* att1 = (const float*)d_in[1];
    const float* obj  = (const float*)d_in[2];
    const int*   tags = (const int*)d_in[3];
    const int*   tptr = (const int*)d_in[4];
    const float* vw   = (const float*)d_in[5];
    const float* vb   = (const float*)d_in[6];
    const float* qw   = (const float*)d_in[7];
    const float* qb   = (const float*)d_in[8];
    const float* lw   = (const float*)d_in[9];
    const float* lb   = (const float*)d_in[10];
    float* out = (float*)d_out;

    float* ub   = (float*)d_ws;                         // [2048][1024] f32   8 MB
    short* Wth  = (short*)(ub + (size_t)B_ * N_ * H_);  // [16][1024][64]     2 MB
    short* objh = Wth + (size_t)B_ * H_ * O_;           // [1024][768]        1.5 MB
    short* objl = objh + (size_t)1024 * VD_;
    short* qh   = objl + (size_t)1024 * VD_;            // [2048][768]        3 MB
    short* ql   = qh + (size_t)2048 * VD_;
    short* vwh  = ql + (size_t)2048 * VD_;              // [1024][768]
    short* vwl  = vwh + (size_t)H_ * VD_;
    short* qwh  = vwl + (size_t)H_ * VD_;
    short* qwl  = qwh + (size_t)H_ * VD_;

    cvt_split<<<960, 256, 0, stream>>>(obj, q, vw, qw, objh, objl, qh, ql,
                                       vwh, vwl, qwh, qwl);
    gemm_split<<<768, 256, 0, stream>>>(objh, objl, qh, ql, vwh, vwl, qwh, qwl,
                                        qb, lw, Wth, ub);
    fused_logits<<<B_ * 64, 256, 0, stream>>>(att1, Wth, ub, vb, tags,
                                              tptr, lb, out);
}

// Round 8
// 61.921 us; speedup vs baseline: 2.5153x; 2.5153x over previous
//
#include <hip/hip_runtime.h>

#define B_ 16
#define N_ 128
#define A_ 32
#define O_ 64
#define VD_ 768
#define H_ 1024

typedef short s16x8 __attribute__((ext_vector_type(8)));
typedef short s16x4 __attribute__((ext_vector_type(4)));
typedef float f32x4 __attribute__((ext_vector_type(4)));

#define MFMA(a, b, c) __builtin_amdgcn_mfma_f32_16x16x32_bf16(a, b, c, 0, 0, 0)

__device__ __forceinline__ short bf_hi(float x) {
    return (short)(__float_as_uint(x) >> 16);
}
__device__ __forceinline__ short bf_lo(float x) {
    float r = x - __uint_as_float(__float_as_uint(x) & 0xffff0000u);
    return (short)(__float_as_uint(r) >> 16);
}
__device__ __forceinline__ void cvt8(const float4& f0, const float4& f1,
                                     s16x8& hi, s16x8& lo) {
    const float ff[8] = {f0.x, f0.y, f0.z, f0.w, f1.x, f1.y, f1.z, f1.w};
    #pragma unroll
    for (int e = 0; e < 8; ++e) { hi[e] = bf_hi(ff[e]); lo[e] = bf_lo(ff[e]); }
}

__device__ __forceinline__ void gload16(const void* g, void* l) {
    __builtin_amdgcn_global_load_lds(
        (const __attribute__((address_space(1))) void*)g,
        (__attribute__((address_space(3))) void*)l, 16, 0, 0);
}

// ---------------------------------------------------------------------------
// Pre-split f32 -> (hi bf16, lo bf16) for obj, q, vw, qw.  (unchanged)
// ---------------------------------------------------------------------------
__global__ __launch_bounds__(256)
void cvt_split(const float* __restrict__ obj, const float* __restrict__ q,
               const float* __restrict__ vw, const float* __restrict__ qw,
               short* __restrict__ objh, short* __restrict__ objl,
               short* __restrict__ qh, short* __restrict__ ql,
               short* __restrict__ vwh, short* __restrict__ vwl,
               short* __restrict__ qwh, short* __restrict__ qwl)
{
    const int bid = blockIdx.x;
    const float* src; short* hi; short* lo; int base4;
    if (bid < 192)      { src = obj; hi = objh; lo = objl; base4 = bid * 1024; }
    else if (bid < 576) { src = q;   hi = qh;   lo = ql;   base4 = (bid - 192) * 1024; }
    else if (bid < 768) { src = vw;  hi = vwh;  lo = vwl;  base4 = (bid - 576) * 1024; }
    else                { src = qw;  hi = qwh;  lo = qwl;  base4 = (bid - 768) * 1024; }
    #pragma unroll
    for (int it = 0; it < 4; ++it) {
        const size_t f4 = (size_t)base4 + it * 256 + threadIdx.x;
        const float4 v = *(const float4*)(src + f4 * 4);
        const float ff[4] = {v.x, v.y, v.z, v.w};
        s16x4 h4, l4;
        #pragma unroll
        for (int e = 0; e < 4; ++e) { h4[e] = bf_hi(ff[e]); l4[e] = bf_lo(ff[e]); }
        *(s16x4*)(hi + f4 * 4) = h4;
        *(s16x4*)(lo + f4 * 4) = l4;
    }
}

// ---------------------------------------------------------------------------
// Unified split-bf16 NT GEMM on pre-split operands (unchanged; verified).
// ---------------------------------------------------------------------------
__global__ __launch_bounds__(256)
void gemm_split(const short* __restrict__ objh, const short* __restrict__ objl,
                const short* __restrict__ qh, const short* __restrict__ ql,
                const short* __restrict__ vwh, const short* __restrict__ vwl,
                const short* __restrict__ qwh, const short* __restrict__ qwl,
                const float* __restrict__ qb, const float* __restrict__ lwp,
                short* __restrict__ Wth, float* __restrict__ ub)
{
    __shared__ __align__(16) short lds[4 * 4096];   // Xh | Xl | Bh | Bl (64x64 each)
    const int bid = blockIdx.x;
    const bool isA = bid < 256;
    const int lb_ = isA ? bid : bid - 256;
    const int r0 = (lb_ >> 4) * 64;
    const int h0 = (lb_ & 15) * 64;
    const short* Xh = isA ? objh : qh;
    const short* Xl = isA ? objl : ql;
    const short* Bh = isA ? vwh : qwh;
    const short* Bl = isA ? vwl : qwl;

    const int tid = threadIdx.x;
    const int w = tid >> 6, l = tid & 63;
    const int wm = (w >> 1) * 32, wn = (w & 1) * 32;
    const int g = l >> 4, c16 = l & 15;

    const int row0 = tid >> 3, u0 = (tid & 7) ^ (row0 & 7);
    const int unit1 = 256 + tid;
    const int row1 = unit1 >> 3, u1 = (unit1 & 7) ^ (row1 & 7);
    const short* pXh = Xh + (size_t)r0 * VD_;
    const short* pXl = Xl + (size_t)r0 * VD_;
    const short* pBh = Bh + (size_t)h0 * VD_;
    const short* pBl = Bl + (size_t)h0 * VD_;
    int go0 = row0 * VD_ + u0 * 8;
    int go1 = row1 * VD_ + u1 * 8;
    short* const d0 = &lds[w * 512];

    f32x4 acc[2][2] = {};

    for (int c = 0; c < VD_ / 64; ++c) {
        __syncthreads();
        gload16(pXh + go0, d0);
        gload16(pXh + go1, d0 + 2048);
        gload16(pXl + go0, d0 + 4096);
        gload16(pXl + go1, d0 + 4096 + 2048);
        gload16(pBh + go0, d0 + 8192);
        gload16(pBh + go1, d0 + 8192 + 2048);
        gload16(pBl + go0, d0 + 12288);
        gload16(pBl + go1, d0 + 12288 + 2048);
        go0 += 64; go1 += 64;
        __syncthreads();
        #pragma unroll
        for (int s = 0; s < 2; ++s) {
            s16x8 ah[2], al[2], bh2[2], bl2[2];
            #pragma unroll
            for (int i = 0; i < 2; ++i) {
                const int m = wm + i * 16 + c16;
                const int us = (((s * 4 + g) ^ (m & 7)) * 8);
                ah[i]  = *(const s16x8*)&lds[m * 64 + us];
                al[i]  = *(const s16x8*)&lds[4096 + m * 64 + us];
                const int n = wn + i * 16 + c16;
                const int vs = (((s * 4 + g) ^ (n & 7)) * 8);
                bh2[i] = *(const s16x8*)&lds[8192 + n * 64 + vs];
                bl2[i] = *(const s16x8*)&lds[12288 + n * 64 + vs];
            }
            #pragma unroll
            for (int i = 0; i < 2; ++i)
                #pragma unroll
                for (int j = 0; j < 2; ++j) {
                    acc[i][j] = MFMA(ah[i], bh2[j], acc[i][j]);
                    acc[i][j] = MFMA(ah[i], bl2[j], acc[i][j]);
                    acc[i][j] = MFMA(al[i], bh2[j], acc[i][j]);
                }
        }
    }

    #pragma unroll
    for (int i = 0; i < 2; ++i)
        #pragma unroll
        for (int j = 0; j < 2; ++j) {
            const int h = h0 + wn + j * 16 + c16;
            if (isA) {
                const int o = wm + i * 16 + g * 4;
                s16x4 hi4;
                #pragma unroll
                for (int r = 0; r < 4; ++r) hi4[r] = bf_hi(acc[i][j][r]);
                const size_t dst = ((size_t)(lb_ >> 4) * H_ + h) * O_ + o;
                *(s16x4*)&Wth[dst] = hi4;
            } else {
                const float bv = qb[h], sv = lwp[h];
                #pragma unroll
                for (int r = 0; r < 4; ++r) {
                    const int m = r0 + wm + i * 16 + g * 4 + r;
                    ub[(size_t)m * H_ + h] = fmaxf(acc[i][j][r] + bv, 0.f) * sv;
                }
            }
        }
}

// ---------------------------------------------------------------------------
// Fused v4: per (b, n-pair) block. WAVE-PRIVATE W staging: each wave stages
// its own 16-h slab (2 KB) of each chunk into its own LDS region and reads
// only that -> ZERO barriers in the chunk loop. Ordering is per-wave counted
// s_waitcnt vmcnt(2) (the deepest prefetch stays in flight; vmcnt(0) only at
// the tail). u/vb live in LDS tables (no runtime-indexed register arrays),
// addresses computed from runtime t (no unroll-time address precompute).
// LDS 45 KB -> 3 blocks/CU. Compute math identical to the verified v2.
// ---------------------------------------------------------------------------
__global__ __launch_bounds__(256, 3)
void fused_logits(const float* __restrict__ att1, const short* __restrict__ Wth,
                  const float* __restrict__ ub, const float* __restrict__ vb,
                  const int* __restrict__ tags, const int* __restrict__ tptr,
                  const float* __restrict__ lbptr, float* __restrict__ out)
{
    __shared__ __align__(16) short Ah[64 * 64], Al[64 * 64];   // 16 KB
    __shared__ __align__(16) short Wc[2][4096];                // 16 KB: [buf][w*1024 + slab]
    __shared__ float ut[2][1024];                              // 8 KB (u rows n0,n0+1)
    __shared__ float vbl[1024];                                // 4 KB
    __shared__ float lgp[4][64];                               // 1 KB

    const int blk = blockIdx.x;          // b*64 + pair
    const int b = blk >> 6;
    const int n0 = (blk & 63) * 2;
    const int tid = threadIdx.x;
    const size_t base_row = (size_t)(b * N_ + n0) * A_;

    const int w = tid >> 6, l = tid & 63;
    const int g = l >> 4, c16 = l & 15;

    // ---- wave-private W staging geometry --------------------------------
    // slab = 16 h-rows (w*16 .. w*16+15) x 64 o, row-major [16][64] shorts in
    // LDS with source col-unit pre-swizzle cu = j ^ (r&7) (read undoes it).
    const int r0l = l >> 3;                  // 0..7 (k=0 row; k=1 row = r0l+8)
    const int cu  = (l & 7) ^ r0l;           // source col-unit (same for k=0,1)
    const short* pW = Wth + (size_t)b * (H_ * O_) + w * 1024 + r0l * 64 + cu * 8;
    short* const dW = &Wc[0][w * 1024 + l * 8];   // + buf*4096; k=1 at +512

#define STAGEW(BUFOFF, CI) do { \
        const short* ph_ = pW + (size_t)(CI) * 4096; \
        gload16(ph_,       dW + (BUFOFF)); \
        gload16(ph_ + 512, dW + (BUFOFF) + 512); \
    } while (0)

    STAGEW(0, 0);                            // chunk 0 -> buf 0 (pre-barrier)

    {   // stage att1 tile as swizzled split-bf16 (once per pair)
        const int row = tid >> 2, qq = tid & 3;
        const float* src = att1 + (base_row + row) * O_ + qq * 16;
        #pragma unroll
        for (int uu = 0; uu < 2; ++uu) {
            const float4 f0 = *(const float4*)(src + uu * 8);
            const float4 f1 = *(const float4*)(src + uu * 8 + 4);
            const int us = ((qq * 2 + uu) ^ (row & 7)) * 8;
            s16x8 hi, lo; cvt8(f0, f1, hi, lo);
            *(s16x8*)&Ah[row * 64 + us] = hi;
            *(s16x8*)&Al[row * 64 + us] = lo;
        }
    }

    {   // u rows and vb -> LDS tables (float4 coalesced)
        const float* u0g = ub + (size_t)(b * N_ + n0) * H_;
        const float* u1g = u0g + H_;
        *(float4*)&ut[0][tid * 4] = *(const float4*)(u0g + tid * 4);
        *(float4*)&ut[1][tid * 4] = *(const float4*)(u1g + tid * 4);
        *(float4*)&vbl[tid * 4]   = *(const float4*)(vb + tid * 4);
    }

    __syncthreads();     // full drain: vmcnt baseline 0, A/u/vb/chunk0 visible

    // A fragments, held for the whole sweep (16 frags = 64 VGPRs)
    s16x8 ahf[4][2], alf[4][2];
    #pragma unroll
    for (int i = 0; i < 4; ++i)
        #pragma unroll
        for (int s = 0; s < 2; ++s) {
            const int m = i * 16 + c16;
            const int us = ((s * 4 + g) ^ (m & 7)) * 8;
            ahf[i][s] = *(const s16x8*)&Ah[m * 64 + us];
            alf[i][s] = *(const s16x8*)&Al[m * 64 + us];
        }

    const int sr = c16 & 7;
    const int rb = w * 1024 + c16 * 64;      // slab row base (this lane's h-row)
    const int ubo0 = (g ^ sr) * 8;
    const int ubo1 = ((g + 4) ^ sr) * 8;
    const int ulane = w * 16 + c16;

    f32x4 part[4] = {};

    // Per-wave pipeline, no barriers. Ledger (2 loads per STAGE):
    // iter t: issue s(t+1) -> outstanding {s(t)?, s(t+1)} <= 4;
    // vmcnt(2) retires s(t) (this iter's chunk); s(t+1) stays in flight.
    #pragma unroll 2
    for (int t = 0; t < 16; ++t) {
        if (t < 15) {
            STAGEW(((t + 1) & 1) * 4096, t + 1);
            asm volatile("s_waitcnt vmcnt(2)" ::: "memory");
        } else {
            asm volatile("s_waitcnt vmcnt(0)" ::: "memory");
        }
        const int bufo = (t & 1) * 4096;
        const float vbv = vbl[t * 64 + ulane];
        const float uu0 = ut[0][t * 64 + ulane];
        const float uu1 = ut[1][t * 64 + ulane];
        const s16x8 bh0 = *(const s16x8*)&Wc[0][bufo + rb + ubo0];
        const s16x8 bh1 = *(const s16x8*)&Wc[0][bufo + rb + ubo1];
        #pragma unroll
        for (int i = 0; i < 4; ++i) {
            f32x4 acc = {};
            acc = MFMA(ahf[i][0], bh0, acc);
            acc = MFMA(alf[i][0], bh0, acc);
            acc = MFMA(ahf[i][1], bh1, acc);
            acc = MFMA(alf[i][1], bh1, acc);
            const float uu = (i < 2) ? uu0 : uu1;
            #pragma unroll
            for (int r = 0; r < 4; ++r)
                part[i][r] += fmaxf(acc[r] + vbv, 0.f) * uu;
        }
    }
#undef STAGEW

    __syncthreads();     // all waves done with Wc/ut/vbl before reuse

    #pragma unroll
    for (int i = 0; i < 4; ++i)
        #pragma unroll
        for (int r = 0; r < 4; ++r) {
            float v = part[i][r];
            v += __shfl_xor(v, 1, 64);
            v += __shfl_xor(v, 2, 64);
            v += __shfl_xor(v, 4, 64);
            v += __shfl_xor(v, 8, 64);
            if (c16 == 0) lgp[w][i * 16 + g * 4 + r] = v;
        }
    __syncthreads();

    float* sml = &vbl[0];    // vbl dead after loop; reuse 256 B
    if (tid < 64) {
        const float tf = (float)(*tptr);
        const float lsum = lgp[0][tid] + lgp[1][tid] + lgp[2][tid] + lgp[3][tid];
        const float lv = (lsum + *lbptr) / tf;
        const int tg = tags[base_row + tid];
        sml[tid] = (tg > 0) ? lv : -1e30f;
    }
    __syncthreads();

    if (tid < 128) {
        const int nn = tid >> 6, o = tid & 63;
        const float* lr = &sml[nn * 32];
        const int uo = (o >> 3);          // 8-elem unit of column o
        const int oe = (o & 7);
        float m = -3.0e38f;
        #pragma unroll
        for (int a = 0; a < 32; ++a) m = fmaxf(m, lr[a]);
        float s = 0.f, accum = 0.f;
        #pragma unroll
        for (int a = 0; a < 32; ++a) {
            const int row = nn * 32 + a;
            const int idx = row * 64 + ((uo ^ (row & 7)) * 8 + oe);
            const float a1 =
                __uint_as_float(((unsigned)(unsigned short)Ah[idx]) << 16) +
                __uint_as_float(((unsigned)(unsigned short)Al[idx]) << 16);
            const float e = __expf(lr[a] - m);
            s += e;
            accum += e * a1;
        }
        out[(size_t)(b * N_ + n0 + nn) * O_ + o] = accum / s;
    }
}

extern "C" void kernel_launch(void* const* d_in, const int* in_sizes, int n_in,
                              void* d_out, int out_size, void* d_ws, size_t ws_size,
                              hipStream_t stream)
{
    const float* q    = (const float*)d_in[0];
    const float* att1 = (const float*)d_in[1];
    const float* obj  = (const float*)d_in[2];
    const int*   tags = (const int*)d_in[3];
    const int*   tptr = (const int*)d_in[4];
    const float* vw   = (const float*)d_in[5];
    const float* vb   = (const float*)d_in[6];
    const float* qw   = (const float*)d_in[7];
    const float* qb   = (const float*)d_in[8];
    const float* lw   = (const float*)d_in[9];
    const float* lb   = (const float*)d_in[10];
    float* out = (float*)d_out;

    float* ub   = (float*)d_ws;                         // [2048][1024] f32   8 MB
    short* Wth  = (short*)(ub + (size_t)B_ * N_ * H_);  // [16][1024][64]     2 MB
    short* objh = Wth + (size_t)B_ * H_ * O_;           // [1024][768]        1.5 MB
    short* objl = objh + (size_t)1024 * VD_;
    short* qh   = objl + (size_t)1024 * VD_;            // [2048][768]        3 MB
    short* ql   = qh + (size_t)2048 * VD_;
    short* vwh  = ql + (size_t)2048 * VD_;              // [1024][768]
    short* vwl  = vwh + (size_t)H_ * VD_;
    short* qwh  = vwl + (size_t)H_ * VD_;
    short* qwl  = qwh + (size_t)H_ * VD_;

    cvt_split<<<960, 256, 0, stream>>>(obj, q, vw, qw, objh, objl, qh, ql,
                                       vwh, vwl, qwh, qwl);
    gemm_split<<<768, 256, 0, stream>>>(objh, objl, qh, ql, vwh, vwl, qwh, qwl,
                                        qb, lw, Wth, ub);
    fused_logits<<<B_ * 64, 256, 0, stream>>>(att1, Wth, ub, vb, tags,
                                              tptr, lb, out);
}

// Round 9
// 48.299 us; speedup vs baseline: 3.2246x; 1.2820x over previous
//
#include <hip/hip_runtime.h>

#define B_ 16
#define N_ 128
#define A_ 32
#define O_ 64
#define VD_ 768
#define H_ 1024

typedef short s16x8 __attribute__((ext_vector_type(8)));
typedef short s16x4 __attribute__((ext_vector_type(4)));
typedef float f32x4 __attribute__((ext_vector_type(4)));

#define MFMA(a, b, c) __builtin_amdgcn_mfma_f32_16x16x32_bf16(a, b, c, 0, 0, 0)

__device__ __forceinline__ short bf_hi(float x) {
    return (short)(__float_as_uint(x) >> 16);
}
__device__ __forceinline__ short bf_lo(float x) {
    float r = x - __uint_as_float(__float_as_uint(x) & 0xffff0000u);
    return (short)(__float_as_uint(r) >> 16);
}

__device__ __forceinline__ void gload16(const void* g, void* l) {
    __builtin_amdgcn_global_load_lds(
        (const __attribute__((address_space(1))) void*)g,
        (__attribute__((address_space(3))) void*)l, 16, 0, 0);
}

// ---------------------------------------------------------------------------
// Pre-split f32 -> bf16 for obj, q (hi+lo) and vw, qw (hi only; B-side of the
// 2-term exact-A x rounded-B scheme never needs lo).
// ---------------------------------------------------------------------------
__global__ __launch_bounds__(256)
void cvt_split(const float* __restrict__ obj, const float* __restrict__ q,
               const float* __restrict__ vw, const float* __restrict__ qw,
               short* __restrict__ objh, short* __restrict__ objl,
               short* __restrict__ qh, short* __restrict__ ql,
               short* __restrict__ vwh, short* __restrict__ qwh)
{
    const int bid = blockIdx.x;
    const float* src; short* hi; short* lo; int base4;
    if (bid < 192)      { src = obj; hi = objh; lo = objl; base4 = bid * 1024; }
    else if (bid < 576) { src = q;   hi = qh;   lo = ql;   base4 = (bid - 192) * 1024; }
    else if (bid < 768) { src = vw;  hi = vwh;  lo = nullptr; base4 = (bid - 576) * 1024; }
    else                { src = qw;  hi = qwh;  lo = nullptr; base4 = (bid - 768) * 1024; }
    #pragma unroll
    for (int it = 0; it < 4; ++it) {
        const size_t f4 = (size_t)base4 + it * 256 + threadIdx.x;
        const float4 v = *(const float4*)(src + f4 * 4);
        const float ff[4] = {v.x, v.y, v.z, v.w};
        s16x4 h4;
        #pragma unroll
        for (int e = 0; e < 4; ++e) h4[e] = bf_hi(ff[e]);
        *(s16x4*)(hi + f4 * 4) = h4;
        if (lo) {
            s16x4 l4;
            #pragma unroll
            for (int e = 0; e < 4; ++e) l4[e] = bf_lo(ff[e]);
            *(s16x4*)(lo + f4 * 4) = l4;
        }
    }
}

// ---------------------------------------------------------------------------
// Unified NT GEMM: exact-X (hi+lo) x rounded-B (hi only), 2 MFMA per frag.
// Blocks [0,256):  W[b][h][o] (transposed bf16-hi) = obj[b*64+o,:] . vw[h,:]
// Blocks [256,768): u[m][h] f32 = relu(q[m,:] . qw[h,:] + qb[h]) * lw[h]
// ---------------------------------------------------------------------------
__global__ __launch_bounds__(256)
void gemm_split(const short* __restrict__ objh, const short* __restrict__ objl,
                const short* __restrict__ qh, const short* __restrict__ ql,
                const short* __restrict__ vwh, const short* __restrict__ qwh,
                const float* __restrict__ qb, const float* __restrict__ lwp,
                short* __restrict__ Wth, float* __restrict__ ub)
{
    __shared__ __align__(16) short lds[3 * 4096];   // Xh | Xl | Bh (64x64 each)
    const int bid = blockIdx.x;
    const bool isA = bid < 256;
    const int lb_ = isA ? bid : bid - 256;
    const int r0 = (lb_ >> 4) * 64;
    const int h0 = (lb_ & 15) * 64;
    const short* Xh = isA ? objh : qh;
    const short* Xl = isA ? objl : ql;
    const short* Bh = isA ? vwh : qwh;

    const int tid = threadIdx.x;
    const int w = tid >> 6, l = tid & 63;
    const int wm = (w >> 1) * 32, wn = (w & 1) * 32;
    const int g = l >> 4, c16 = l & 15;

    const int row0 = tid >> 3, u0 = (tid & 7) ^ (row0 & 7);
    const int unit1 = 256 + tid;
    const int row1 = unit1 >> 3, u1 = (unit1 & 7) ^ (row1 & 7);
    const short* pXh = Xh + (size_t)r0 * VD_;
    const short* pXl = Xl + (size_t)r0 * VD_;
    const short* pBh = Bh + (size_t)h0 * VD_;
    int go0 = row0 * VD_ + u0 * 8;
    int go1 = row1 * VD_ + u1 * 8;
    short* const d0 = &lds[w * 512];

    f32x4 acc[2][2] = {};

    for (int c = 0; c < VD_ / 64; ++c) {
        __syncthreads();
        gload16(pXh + go0, d0);
        gload16(pXh + go1, d0 + 2048);
        gload16(pXl + go0, d0 + 4096);
        gload16(pXl + go1, d0 + 4096 + 2048);
        gload16(pBh + go0, d0 + 8192);
        gload16(pBh + go1, d0 + 8192 + 2048);
        go0 += 64; go1 += 64;
        __syncthreads();
        #pragma unroll
        for (int s = 0; s < 2; ++s) {
            s16x8 ah[2], al[2], bh2[2];
            #pragma unroll
            for (int i = 0; i < 2; ++i) {
                const int m = wm + i * 16 + c16;
                const int us = (((s * 4 + g) ^ (m & 7)) * 8);
                ah[i]  = *(const s16x8*)&lds[m * 64 + us];
                al[i]  = *(const s16x8*)&lds[4096 + m * 64 + us];
                const int n = wn + i * 16 + c16;
                const int vs = (((s * 4 + g) ^ (n & 7)) * 8);
                bh2[i] = *(const s16x8*)&lds[8192 + n * 64 + vs];
            }
            #pragma unroll
            for (int i = 0; i < 2; ++i)
                #pragma unroll
                for (int j = 0; j < 2; ++j) {
                    acc[i][j] = MFMA(ah[i], bh2[j], acc[i][j]);
                    acc[i][j] = MFMA(al[i], bh2[j], acc[i][j]);
                }
        }
    }

    #pragma unroll
    for (int i = 0; i < 2; ++i)
        #pragma unroll
        for (int j = 0; j < 2; ++j) {
            const int h = h0 + wn + j * 16 + c16;
            if (isA) {
                const int o = wm + i * 16 + g * 4;
                s16x4 hi4;
                #pragma unroll
                for (int r = 0; r < 4; ++r) hi4[r] = bf_hi(acc[i][j][r]);
                const size_t dst = ((size_t)(lb_ >> 4) * H_ + h) * O_ + o;
                *(s16x4*)&Wth[dst] = hi4;
            } else {
                const float bv = qb[h], sv = lwp[h];
                #pragma unroll
                for (int r = 0; r < 4; ++r) {
                    const int m = r0 + wm + i * 16 + g * 4 + r;
                    ub[(size_t)m * H_ + h] = fmaxf(acc[i][j][r] + bv, 0.f) * sv;
                }
            }
        }
}

// ---------------------------------------------------------------------------
// Fused v5: per (b, n-pair) block. Wave-private W staging (zero barriers in
// the chunk loop, counted vmcnt(2) per wave — verified v4 pipeline). MFMA is
// now rounded-A x rounded-W (hi x hi): 8 MFMA/chunk. att1-lo dropped from
// LDS; the softmax epilogue reads exact f32 att1 from global (L2-hot).
// LDS 37 KB -> 4 blocks/CU.
// ---------------------------------------------------------------------------
__global__ __launch_bounds__(256, 4)
void fused_logits(const float* __restrict__ att1, const short* __restrict__ Wth,
                  const float* __restrict__ ub, const float* __restrict__ vb,
                  const int* __restrict__ tags, const int* __restrict__ tptr,
                  const float* __restrict__ lbptr, float* __restrict__ out)
{
    __shared__ __align__(16) short Ah[64 * 64];                // 8 KB
    __shared__ __align__(16) short Wc[2][4096];                // 16 KB: [buf][w*1024+slab]
    __shared__ float ut[2][1024];                              // 8 KB (u rows n0,n0+1)
    __shared__ float vbl[1024];                                // 4 KB
    __shared__ float lgp[4][64];                               // 1 KB

    const int blk = blockIdx.x;          // b*64 + pair
    const int b = blk >> 6;
    const int n0 = (blk & 63) * 2;
    const int tid = threadIdx.x;
    const size_t base_row = (size_t)(b * N_ + n0) * A_;

    const int w = tid >> 6, l = tid & 63;
    const int g = l >> 4, c16 = l & 15;

    // ---- wave-private W staging geometry (unchanged from v4) ------------
    const int r0l = l >> 3;                  // 0..7 (k=0 row; k=1 row = r0l+8)
    const int cu  = (l & 7) ^ r0l;           // source col-unit pre-swizzle
    const short* pW = Wth + (size_t)b * (H_ * O_) + w * 1024 + r0l * 64 + cu * 8;
    short* const dW = &Wc[0][w * 1024 + l * 8];   // + buf*4096; k=1 at +512

#define STAGEW(BUFOFF, CI) do { \
        const short* ph_ = pW + (size_t)(CI) * 4096; \
        gload16(ph_,       dW + (BUFOFF)); \
        gload16(ph_ + 512, dW + (BUFOFF) + 512); \
    } while (0)

    STAGEW(0, 0);                            // chunk 0 -> buf 0 (pre-barrier)

    {   // stage att1 tile as swizzled bf16-hi (once per pair)
        const int row = tid >> 2, qq = tid & 3;
        const float* src = att1 + (base_row + row) * O_ + qq * 16;
        #pragma unroll
        for (int uu = 0; uu < 2; ++uu) {
            const float4 f0 = *(const float4*)(src + uu * 8);
            const float4 f1 = *(const float4*)(src + uu * 8 + 4);
            const float ff[8] = {f0.x, f0.y, f0.z, f0.w, f1.x, f1.y, f1.z, f1.w};
            const int us = ((qq * 2 + uu) ^ (row & 7)) * 8;
            s16x8 hi;
            #pragma unroll
            for (int e = 0; e < 8; ++e) hi[e] = bf_hi(ff[e]);
            *(s16x8*)&Ah[row * 64 + us] = hi;
        }
    }

    {   // u rows and vb -> LDS tables (float4 coalesced)
        const float* u0g = ub + (size_t)(b * N_ + n0) * H_;
        const float* u1g = u0g + H_;
        *(float4*)&ut[0][tid * 4] = *(const float4*)(u0g + tid * 4);
        *(float4*)&ut[1][tid * 4] = *(const float4*)(u1g + tid * 4);
        *(float4*)&vbl[tid * 4]   = *(const float4*)(vb + tid * 4);
    }

    __syncthreads();     // full drain: vmcnt baseline 0, A/u/vb/chunk0 visible

    // A fragments (hi only), held for the whole sweep: 8 frags = 32 VGPRs
    s16x8 ahf[4][2];
    #pragma unroll
    for (int i = 0; i < 4; ++i)
        #pragma unroll
        for (int s = 0; s < 2; ++s) {
            const int m = i * 16 + c16;
            const int us = ((s * 4 + g) ^ (m & 7)) * 8;
            ahf[i][s] = *(const s16x8*)&Ah[m * 64 + us];
        }

    const int sr = c16 & 7;
    const int rb = w * 1024 + c16 * 64;      // slab row base (this lane's h-row)
    const int ubo0 = (g ^ sr) * 8;
    const int ubo1 = ((g + 4) ^ sr) * 8;
    const int ulane = w * 16 + c16;

    f32x4 part[4] = {};

    // Per-wave pipeline, no barriers (ledger: vmcnt(2) retires chunk t).
    #pragma unroll 2
    for (int t = 0; t < 16; ++t) {
        if (t < 15) {
            STAGEW(((t + 1) & 1) * 4096, t + 1);
            asm volatile("s_waitcnt vmcnt(2)" ::: "memory");
        } else {
            asm volatile("s_waitcnt vmcnt(0)" ::: "memory");
        }
        const int bufo = (t & 1) * 4096;
        const float vbv = vbl[t * 64 + ulane];
        const float uu0 = ut[0][t * 64 + ulane];
        const float uu1 = ut[1][t * 64 + ulane];
        const s16x8 bh0 = *(const s16x8*)&Wc[0][bufo + rb + ubo0];
        const s16x8 bh1 = *(const s16x8*)&Wc[0][bufo + rb + ubo1];
        #pragma unroll
        for (int i = 0; i < 4; ++i) {
            f32x4 acc = {};
            acc = MFMA(ahf[i][0], bh0, acc);
            acc = MFMA(ahf[i][1], bh1, acc);
            const float uu = (i < 2) ? uu0 : uu1;
            #pragma unroll
            for (int r = 0; r < 4; ++r)
                part[i][r] += fmaxf(acc[r] + vbv, 0.f) * uu;
        }
    }
#undef STAGEW

    __syncthreads();     // all waves done with Wc/ut/vbl before reuse

    #pragma unroll
    for (int i = 0; i < 4; ++i)
        #pragma unroll
        for (int r = 0; r < 4; ++r) {
            float v = part[i][r];
            v += __shfl_xor(v, 1, 64);
            v += __shfl_xor(v, 2, 64);
            v += __shfl_xor(v, 4, 64);
            v += __shfl_xor(v, 8, 64);
            if (c16 == 0) lgp[w][i * 16 + g * 4 + r] = v;
        }
    __syncthreads();

    float* sml = &vbl[0];    // vbl dead after loop; reuse 256 B
    if (tid < 64) {
        const float tf = (float)(*tptr);
        const float lsum = lgp[0][tid] + lgp[1][tid] + lgp[2][tid] + lgp[3][tid];
        const float lv = (lsum + *lbptr) / tf;
        const int tg = tags[base_row + tid];
        sml[tid] = (tg > 0) ? lv : -1e30f;
    }
    __syncthreads();

    if (tid < 128) {
        const int nn = tid >> 6, o = tid & 63;
        const float* lr = &sml[nn * 32];
        float m = -3.0e38f;
        #pragma unroll
        for (int a = 0; a < 32; ++a) m = fmaxf(m, lr[a]);
        float s = 0.f, accum = 0.f;
        #pragma unroll
        for (int a = 0; a < 32; ++a) {
            const float e = __expf(lr[a] - m);
            s += e;
            accum += e * att1[(base_row + nn * 32 + a) * O_ + o];   // exact f32
        }
        out[(size_t)(b * N_ + n0 + nn) * O_ + o] = accum / s;
    }
}

extern "C" void kernel_launch(void* const* d_in, const int* in_sizes, int n_in,
                              void* d_out, int out_size, void* d_ws, size_t ws_size,
                              hipStream_t stream)
{
    const float* q    = (const float*)d_in[0];
    const float* att1 = (const float*)d_in[1];
    const float* obj  = (const float*)d_in[2];
    const int*   tags = (const int*)d_in[3];
    const int*   tptr = (const int*)d_in[4];
    const float* vw   = (const float*)d_in[5];
    const float* vb   = (const float*)d_in[6];
    const float* qw   = (const float*)d_in[7];
    const float* qb   = (const float*)d_in[8];
    const float* lw   = (const float*)d_in[9];
    const float* lb   = (const float*)d_in[10];
    float* out = (float*)d_out;

    float* ub   = (float*)d_ws;                         // [2048][1024] f32   8 MB
    short* Wth  = (short*)(ub + (size_t)B_ * N_ * H_);  // [16][1024][64]     2 MB
    short* objh = Wth + (size_t)B_ * H_ * O_;           // [1024][768]        1.5 MB
    short* objl = objh + (size_t)1024 * VD_;
    short* qh   = objl + (size_t)1024 * VD_;            // [2048][768]        3 MB
    short* ql   = qh + (size_t)2048 * VD_;
    short* vwh  = ql + (size_t)2048 * VD_;              // [1024][768] hi     1.5 MB
    short* qwh  = vwh + (size_t)H_ * VD_;               // [1024][768] hi     1.5 MB

    cvt_split<<<960, 256, 0, stream>>>(obj, q, vw, qw, objh, objl, qh, ql,
                                       vwh, qwh);
    gemm_split<<<768, 256, 0, stream>>>(objh, objl, qh, ql, vwh, qwh,
                                        qb, lw, Wth, ub);
    fused_logits<<<B_ * 64, 256, 0, stream>>>(att1, Wth, ub, vb, tags,
                                              tptr, lb, out);
}

// Round 10
// 46.286 us; speedup vs baseline: 3.3649x; 1.0435x over previous
//
#include <hip/hip_runtime.h>

#define B_ 16
#define N_ 128
#define A_ 32
#define O_ 64
#define VD_ 768
#define H_ 1024

typedef short s16x8 __attribute__((ext_vector_type(8)));
typedef short s16x4 __attribute__((ext_vector_type(4)));
typedef float f32x4 __attribute__((ext_vector_type(4)));

#define MFMA(a, b, c) __builtin_amdgcn_mfma_f32_16x16x32_bf16(a, b, c, 0, 0, 0)

__device__ __forceinline__ short bf_hi(float x) {
    return (short)(__float_as_uint(x) >> 16);
}
__device__ __forceinline__ short bf_lo(float x) {
    float r = x - __uint_as_float(__float_as_uint(x) & 0xffff0000u);
    return (short)(__float_as_uint(r) >> 16);
}

__device__ __forceinline__ void gload16(const void* g, void* l) {
    __builtin_amdgcn_global_load_lds(
        (const __attribute__((address_space(1))) void*)g,
        (__attribute__((address_space(3))) void*)l, 16, 0, 0);
}

// ---------------------------------------------------------------------------
// Pre-split f32 -> bf16: obj hi, q hi+lo, vw hi, qw hi.
// (obj-lo dropped: W is stored bf16-hi anyway, so obj-lo is below the noise.)
// ---------------------------------------------------------------------------
__global__ __launch_bounds__(256)
void cvt_split(const float* __restrict__ obj, const float* __restrict__ q,
               const float* __restrict__ vw, const float* __restrict__ qw,
               short* __restrict__ objh,
               short* __restrict__ qh, short* __restrict__ ql,
               short* __restrict__ vwh, short* __restrict__ qwh)
{
    const int bid = blockIdx.x;
    const float* src; short* hi; short* lo; int base4;
    if (bid < 192)      { src = obj; hi = objh; lo = nullptr; base4 = bid * 1024; }
    else if (bid < 576) { src = q;   hi = qh;   lo = ql;      base4 = (bid - 192) * 1024; }
    else if (bid < 768) { src = vw;  hi = vwh;  lo = nullptr; base4 = (bid - 576) * 1024; }
    else                { src = qw;  hi = qwh;  lo = nullptr; base4 = (bid - 768) * 1024; }
    #pragma unroll
    for (int it = 0; it < 4; ++it) {
        const size_t f4 = (size_t)base4 + it * 256 + threadIdx.x;
        const float4 v = *(const float4*)(src + f4 * 4);
        const float ff[4] = {v.x, v.y, v.z, v.w};
        s16x4 h4;
        #pragma unroll
        for (int e = 0; e < 4; ++e) h4[e] = bf_hi(ff[e]);
        *(s16x4*)(hi + f4 * 4) = h4;
        if (lo) {
            s16x4 l4;
            #pragma unroll
            for (int e = 0; e < 4; ++e) l4[e] = bf_lo(ff[e]);
            *(s16x4*)(lo + f4 * 4) = l4;
        }
    }
}

// ---------------------------------------------------------------------------
// Unified NT GEMM, counted-vmcnt double-buffered pipeline (no vmcnt(0) drain
// in steady state). Blocks [0,256): W[b][h][o] bf16-hi = objh[64o,:].vwh[h,:]
// (1 MFMA term). Blocks [256,768): u f32 = relu((qh+ql).qwh + qb)*lw (2 terms).
// Per chunk: vmcnt(NL) -> barrier -> compute -> lgkmcnt(0) -> barrier ->
// STAGE(c+2). Ledger: outstanding <= stage(c)+stage(c+1) = 2*NL, so vmcnt(NL)
// retires stage(c); vmcnt(0) only at the last chunk.
// ---------------------------------------------------------------------------
__global__ __launch_bounds__(256)
void gemm_split(const short* __restrict__ objh,
                const short* __restrict__ qh, const short* __restrict__ ql,
                const short* __restrict__ vwh, const short* __restrict__ qwh,
                const float* __restrict__ qb, const float* __restrict__ lwp,
                short* __restrict__ Wth, float* __restrict__ ub)
{
    __shared__ __align__(16) short lds[2][3][4096];   // [buf][Xh|Xl|Bh][64x64]
    const int bid = blockIdx.x;
    const bool isA = bid < 256;
    const int lb_ = isA ? bid : bid - 256;
    const int r0 = (lb_ >> 4) * 64;
    const int h0 = (lb_ & 15) * 64;
    const short* Xh = isA ? objh : qh;
    const short* Xl = ql;                    // only used when !isA
    const short* Bh = isA ? vwh : qwh;

    const int tid = threadIdx.x;
    const int w = tid >> 6, l = tid & 63;
    const int wm = (w >> 1) * 32, wn = (w & 1) * 32;
    const int g = l >> 4, c16 = l & 15;

    const int row0 = tid >> 3, u0 = (tid & 7) ^ (row0 & 7);
    const int unit1 = 256 + tid;
    const int row1 = unit1 >> 3, u1 = (unit1 & 7) ^ (row1 & 7);
    const short* pXh = Xh + (size_t)r0 * VD_;
    const short* pXl = Xl + (size_t)r0 * VD_;
    const short* pBh = Bh + (size_t)h0 * VD_;
    const int go0 = row0 * VD_ + u0 * 8;
    const int go1 = row1 * VD_ + u1 * 8;
    const int wo = w * 512;

#define STAGE(BUF, CI) do { \
        const int co_ = (CI) * 64; \
        gload16(pXh + go0 + co_, &lds[BUF][0][wo]); \
        gload16(pXh + go1 + co_, &lds[BUF][0][wo + 2048]); \
        if (!isA) { \
            gload16(pXl + go0 + co_, &lds[BUF][1][wo]); \
            gload16(pXl + go1 + co_, &lds[BUF][1][wo + 2048]); \
        } \
        gload16(pBh + go0 + co_, &lds[BUF][2][wo]); \
        gload16(pBh + go1 + co_, &lds[BUF][2][wo + 2048]); \
    } while (0)

    STAGE(0, 0);
    STAGE(1, 1);

    f32x4 acc[2][2] = {};

    #pragma unroll 2
    for (int c = 0; c < VD_ / 64; ++c) {
        if (c < VD_ / 64 - 1) {
            if (isA) asm volatile("s_waitcnt vmcnt(4)" ::: "memory");
            else     asm volatile("s_waitcnt vmcnt(6)" ::: "memory");
        } else {
            asm volatile("s_waitcnt vmcnt(0)" ::: "memory");
        }
        asm volatile("s_barrier" ::: "memory");   // all waves' stage(c) landed

        const short* bXh = &lds[c & 1][0][0];
        const short* bXl = &lds[c & 1][1][0];
        const short* bBh = &lds[c & 1][2][0];
        #pragma unroll
        for (int s = 0; s < 2; ++s) {
            s16x8 ah[2], al[2], bh2[2];
            #pragma unroll
            for (int i = 0; i < 2; ++i) {
                const int m = wm + i * 16 + c16;
                const int us = (((s * 4 + g) ^ (m & 7)) * 8);
                ah[i]  = *(const s16x8*)&bXh[m * 64 + us];
                if (!isA) al[i] = *(const s16x8*)&bXl[m * 64 + us];
                const int n = wn + i * 16 + c16;
                const int vs = (((s * 4 + g) ^ (n & 7)) * 8);
                bh2[i] = *(const s16x8*)&bBh[n * 64 + vs];
            }
            #pragma unroll
            for (int i = 0; i < 2; ++i)
                #pragma unroll
                for (int j = 0; j < 2; ++j) {
                    acc[i][j] = MFMA(ah[i], bh2[j], acc[i][j]);
                    if (!isA) acc[i][j] = MFMA(al[i], bh2[j], acc[i][j]);
                }
        }

        asm volatile("s_waitcnt lgkmcnt(0)" ::: "memory");
        __builtin_amdgcn_sched_barrier(0);
        asm volatile("s_barrier" ::: "memory");   // all waves done reading buf
        if (c + 2 < VD_ / 64) STAGE(c & 1, c + 2);
    }
#undef STAGE

    #pragma unroll
    for (int i = 0; i < 2; ++i)
        #pragma unroll
        for (int j = 0; j < 2; ++j) {
            const int h = h0 + wn + j * 16 + c16;
            if (isA) {
                const int o = wm + i * 16 + g * 4;
                s16x4 hi4;
                #pragma unroll
                for (int r = 0; r < 4; ++r) hi4[r] = bf_hi(acc[i][j][r]);
                const size_t dst = ((size_t)(lb_ >> 4) * H_ + h) * O_ + o;
                *(s16x4*)&Wth[dst] = hi4;
            } else {
                const float bv = qb[h], sv = lwp[h];
                #pragma unroll
                for (int r = 0; r < 4; ++r) {
                    const int m = r0 + wm + i * 16 + g * 4 + r;
                    ub[(size_t)m * H_ + h] = fmaxf(acc[i][j][r] + bv, 0.f) * sv;
                }
            }
        }
}

// ---------------------------------------------------------------------------
// Fused v5 (unchanged, verified): wave-private W staging, zero barriers in
// the chunk loop, counted vmcnt(2); hi x hi MFMA; epilogue reads exact f32
// att1 from global. LDS 37 KB -> 4 blocks/CU.
// ---------------------------------------------------------------------------
__global__ __launch_bounds__(256, 4)
void fused_logits(const float* __restrict__ att1, const short* __restrict__ Wth,
                  const float* __restrict__ ub, const float* __restrict__ vb,
                  const int* __restrict__ tags, const int* __restrict__ tptr,
                  const float* __restrict__ lbptr, float* __restrict__ out)
{
    __shared__ __align__(16) short Ah[64 * 64];                // 8 KB
    __shared__ __align__(16) short Wc[2][4096];                // 16 KB
    __shared__ float ut[2][1024];                              // 8 KB
    __shared__ float vbl[1024];                                // 4 KB
    __shared__ float lgp[4][64];                               // 1 KB

    const int blk = blockIdx.x;          // b*64 + pair
    const int b = blk >> 6;
    const int n0 = (blk & 63) * 2;
    const int tid = threadIdx.x;
    const size_t base_row = (size_t)(b * N_ + n0) * A_;

    const int w = tid >> 6, l = tid & 63;
    const int g = l >> 4, c16 = l & 15;

    const int r0l = l >> 3;                  // 0..7
    const int cu  = (l & 7) ^ r0l;           // source col-unit pre-swizzle
    const short* pW = Wth + (size_t)b * (H_ * O_) + w * 1024 + r0l * 64 + cu * 8;
    short* const dW = &Wc[0][w * 1024 + l * 8];

#define STAGEW(BUFOFF, CI) do { \
        const short* ph_ = pW + (size_t)(CI) * 4096; \
        gload16(ph_,       dW + (BUFOFF)); \
        gload16(ph_ + 512, dW + (BUFOFF) + 512); \
    } while (0)

    STAGEW(0, 0);

    {   // stage att1 tile as swizzled bf16-hi
        const int row = tid >> 2, qq = tid & 3;
        const float* src = att1 + (base_row + row) * O_ + qq * 16;
        #pragma unroll
        for (int uu = 0; uu < 2; ++uu) {
            const float4 f0 = *(const float4*)(src + uu * 8);
            const float4 f1 = *(const float4*)(src + uu * 8 + 4);
            const float ff[8] = {f0.x, f0.y, f0.z, f0.w, f1.x, f1.y, f1.z, f1.w};
            const int us = ((qq * 2 + uu) ^ (row & 7)) * 8;
            s16x8 hi;
            #pragma unroll
            for (int e = 0; e < 8; ++e) hi[e] = bf_hi(ff[e]);
            *(s16x8*)&Ah[row * 64 + us] = hi;
        }
    }

    {   // u rows and vb -> LDS tables
        const float* u0g = ub + (size_t)(b * N_ + n0) * H_;
        const float* u1g = u0g + H_;
        *(float4*)&ut[0][tid * 4] = *(const float4*)(u0g + tid * 4);
        *(float4*)&ut[1][tid * 4] = *(const float4*)(u1g + tid * 4);
        *(float4*)&vbl[tid * 4]   = *(const float4*)(vb + tid * 4);
    }

    __syncthreads();     // full drain: vmcnt baseline 0

    s16x8 ahf[4][2];
    #pragma unroll
    for (int i = 0; i < 4; ++i)
        #pragma unroll
        for (int s = 0; s < 2; ++s) {
            const int m = i * 16 + c16;
            const int us = ((s * 4 + g) ^ (m & 7)) * 8;
            ahf[i][s] = *(const s16x8*)&Ah[m * 64 + us];
        }

    const int sr = c16 & 7;
    const int rb = w * 1024 + c16 * 64;
    const int ubo0 = (g ^ sr) * 8;
    const int ubo1 = ((g + 4) ^ sr) * 8;
    const int ulane = w * 16 + c16;

    f32x4 part[4] = {};

    #pragma unroll 2
    for (int t = 0; t < 16; ++t) {
        if (t < 15) {
            STAGEW(((t + 1) & 1) * 4096, t + 1);
            asm volatile("s_waitcnt vmcnt(2)" ::: "memory");
        } else {
            asm volatile("s_waitcnt vmcnt(0)" ::: "memory");
        }
        const int bufo = (t & 1) * 4096;
        const float vbv = vbl[t * 64 + ulane];
        const float uu0 = ut[0][t * 64 + ulane];
        const float uu1 = ut[1][t * 64 + ulane];
        const s16x8 bh0 = *(const s16x8*)&Wc[0][bufo + rb + ubo0];
        const s16x8 bh1 = *(const s16x8*)&Wc[0][bufo + rb + ubo1];
        #pragma unroll
        for (int i = 0; i < 4; ++i) {
            f32x4 acc = {};
            acc = MFMA(ahf[i][0], bh0, acc);
            acc = MFMA(ahf[i][1], bh1, acc);
            const float uu = (i < 2) ? uu0 : uu1;
            #pragma unroll
            for (int r = 0; r < 4; ++r)
                part[i][r] += fmaxf(acc[r] + vbv, 0.f) * uu;
        }
    }
#undef STAGEW

    __syncthreads();

    #pragma unroll
    for (int i = 0; i < 4; ++i)
        #pragma unroll
        for (int r = 0; r < 4; ++r) {
            float v = part[i][r];
            v += __shfl_xor(v, 1, 64);
            v += __shfl_xor(v, 2, 64);
            v += __shfl_xor(v, 4, 64);
            v += __shfl_xor(v, 8, 64);
            if (c16 == 0) lgp[w][i * 16 + g * 4 + r] = v;
        }
    __syncthreads();

    float* sml = &vbl[0];
    if (tid < 64) {
        const float tf = (float)(*tptr);
        const float lsum = lgp[0][tid] + lgp[1][tid] + lgp[2][tid] + lgp[3][tid];
        const float lv = (lsum + *lbptr) / tf;
        const int tg = tags[base_row + tid];
        sml[tid] = (tg > 0) ? lv : -1e30f;
    }
    __syncthreads();

    if (tid < 128) {
        const int nn = tid >> 6, o = tid & 63;
        const float* lr = &sml[nn * 32];
        float m = -3.0e38f;
        #pragma unroll
        for (int a = 0; a < 32; ++a) m = fmaxf(m, lr[a]);
        float s = 0.f, accum = 0.f;
        #pragma unroll
        for (int a = 0; a < 32; ++a) {
            const float e = __expf(lr[a] - m);
            s += e;
            accum += e * att1[(base_row + nn * 32 + a) * O_ + o];
        }
        out[(size_t)(b * N_ + n0 + nn) * O_ + o] = accum / s;
    }
}

extern "C" void kernel_launch(void* const* d_in, const int* in_sizes, int n_in,
                              void* d_out, int out_size, void* d_ws, size_t ws_size,
                              hipStream_t stream)
{
    const float* q    = (const float*)d_in[0];
    const float* att1 = (const float*)d_in[1];
    const float* obj  = (const float*)d_in[2];
    const int*   tags = (const int*)d_in[3];
    const int*   tptr = (const int*)d_in[4];
    const float* vw   = (const float*)d_in[5];
    const float* vb   = (const float*)d_in[6];
    const float* qw   = (const float*)d_in[7];
    const float* qb   = (const float*)d_in[8];
    const float* lw   = (const float*)d_in[9];
    const float* lb   = (const float*)d_in[10];
    float* out = (float*)d_out;

    float* ub   = (float*)d_ws;                         // [2048][1024] f32   8 MB
    short* Wth  = (short*)(ub + (size_t)B_ * N_ * H_);  // [16][1024][64]     2 MB
    short* objh = Wth + (size_t)B_ * H_ * O_;           // [1024][768] hi     1.5 MB
    short* qh   = objh + (size_t)1024 * VD_;            // [2048][768]        3 MB
    short* ql   = qh + (size_t)2048 * VD_;              //                    3 MB
    short* vwh  = ql + (size_t)2048 * VD_;              // [1024][768] hi     1.5 MB
    short* qwh  = vwh + (size_t)H_ * VD_;               // [1024][768] hi     1.5 MB

    cvt_split<<<960, 256, 0, stream>>>(obj, q, vw, qw, objh, qh, ql, vwh, qwh);
    gemm_split<<<768, 256, 0, stream>>>(objh, qh, ql, vwh, qwh,
                                        qb, lw, Wth, ub);
    fused_logits<<<B_ * 64, 256, 0, stream>>>(att1, Wth, ub, vb, tags,
                                              tptr, lb, out);
}